// Round 1
// baseline (220.940 us; speedup 1.0000x reference)
//
#include <hip/hip_runtime.h>

#define NMOL   32
#define NATOM  512
#define NPAIR  32768
#define NB     64
#define HIDDEN 256
#define TOTNATOM (NMOL * NATOM)

__device__ __forceinline__ float bcastf(float v, int l) {
    return __uint_as_float(__builtin_amdgcn_readlane(__float_as_uint(v), (unsigned)l));
}

// ---------------------------------------------------------------------------
// Kernel B: per-pair features -> LDS density (per molecule) -> global atomics
// grid = 32 mol x 8 pair-slices = 256 blocks (1/CU), 1024 threads (16 waves)
// ---------------------------------------------------------------------------
__global__ __launch_bounds__(1024) void pair_kernel(
    const float* __restrict__ cart, const float* __restrict__ shifts,
    const float* __restrict__ centers, const float* __restrict__ widths,
    const float* __restrict__ c_emb, const int* __restrict__ species,
    const int* __restrict__ atom_index,
    float* __restrict__ density_g, float* __restrict__ totvec_g)
{
    __shared__ float dens[NATOM * NB];   // 128 KB
    __shared__ float tv[NATOM * 3];      // 6 KB

    const int tid = threadIdx.x;
    const int mol = blockIdx.x >> 3;
    const int sub = blockIdx.x & 7;

    for (int i = tid; i < NATOM * NB; i += 1024) dens[i] = 0.f;
    for (int i = tid; i < NATOM * 3;  i += 1024) tv[i] = 0.f;
    __syncthreads();

    const int lane = tid & 63;
    const int wave = tid >> 6;
    const float cb = centers[lane];   // lane = basis index
    const float wb = widths[lane];

    const int*   ai0 = atom_index + (size_t)mol * NPAIR;
    const int*   ai1 = ai0 + (size_t)NMOL * NPAIR;
    const float* sh  = shifts + (size_t)mol * NPAIR * 3;
    const float* cm  = cart + (size_t)mol * NATOM * 3;
    const int*   sp  = species + (size_t)mol * NATOM;

    const int pbase = sub * 4096 + wave * 256;

    for (int it = 0; it < 4; ++it) {
        const int p  = pbase + it * 64 + lane;   // lane = pair (phase 1)
        const int i0 = ai0[p];
        const int i1 = ai1[p];
        const float sx = sh[p * 3 + 0], sy = sh[p * 3 + 1], sz = sh[p * 3 + 2];
        const float m = (sx > -1e10f && sy > -1e10f && sz > -1e10f) ? 1.f : 0.f;
        const float dx = (cm[i0 * 3 + 0] - cm[i1 * 3 + 0] + sx) * m;
        const float dy = (cm[i0 * 3 + 1] - cm[i1 * 3 + 1] + sy) * m;
        const float dz = (cm[i0 * 3 + 2] - cm[i1 * 3 + 2] + sz) * m;
        const float d = sqrtf(dx * dx + dy * dy + dz * dz + 1e-12f);
        float fc = 0.f;
        if (d < 5.0f)  // RC, strict
            fc = 0.5f * (__cosf(0.62831853071795864769f * d) + 1.f) * m;  // pi/RC
        const int spc = sp[i1];

        // tot_vec segment-sum (all valid pairs, independent of cutoff)
        atomicAdd(&tv[i0 * 3 + 0], dx);
        atomicAdd(&tv[i0 * 3 + 1], dy);
        atomicAdd(&tv[i0 * 3 + 2], dz);

        // phase 2: lane = basis; only pairs inside cutoff contribute density
        const int packed = (i0 << 3) | spc;
        unsigned long long mask = __ballot(fc > 0.f);
        while (mask) {
            const int jj = (int)__builtin_ctzll(mask);
            mask &= mask - 1;
            const int   bp  = __builtin_amdgcn_readlane((unsigned)packed, (unsigned)jj);
            const float bd  = bcastf(d, jj);
            const float bfc = bcastf(fc, jj);
            const int bi0 = bp >> 3;
            const int bs  = bp & 7;
            const float t = bd - cb;
            const float r = __expf(-wb * t * t) * bfc * c_emb[bs * NB + lane];
            atomicAdd(&dens[bi0 * NB + lane], r);   // ds_add_f32, conflict-free
        }
    }
    __syncthreads();

    // flush partial molecule density/tot_vec to global (8 blocks contend)
    float* dg = density_g + (size_t)mol * NATOM * NB;
    for (int i = tid; i < NATOM * NB; i += 1024) unsafeAtomicAdd(&dg[i], dens[i]);
    float* tg = totvec_g + (size_t)mol * NATOM * 3;
    for (int i = tid; i < NATOM * 3; i += 1024) unsafeAtomicAdd(&tg[i], tv[i]);
}

// ---------------------------------------------------------------------------
// Kernel C: per-atom MLP (64->256->1, silu) + dipole reduction
// grid = 256 blocks x 256 threads; block covers 64 atoms (single molecule)
// wave w owns hidden slice [w*64, w*64+64); W1 column slice in 64 VGPRs
// ---------------------------------------------------------------------------
__global__ __launch_bounds__(256) void nn_kernel(
    const float* __restrict__ density, const float* __restrict__ totvec,
    const float* __restrict__ W1, const float* __restrict__ b1,
    const float* __restrict__ W2, const float* __restrict__ b2,
    float* __restrict__ dipole)
{
    const int lane = threadIdx.x & 63;
    const int wave = threadIdx.x >> 6;
    const int j = wave * 64 + lane;   // hidden unit

    float w1r[64];
#pragma unroll
    for (int b = 0; b < 64; ++b) w1r[b] = W1[b * HIDDEN + j];
    const float b1v = b1[j];
    const float w2v = W2[j];

    __shared__ float partial[64][4];
    const int a0 = blockIdx.x * 64;

    for (int a = 0; a < 64; ++a) {
        const float* drow = density + (size_t)(a0 + a) * NB;  // uniform -> s_load
        float h0 = 0.f, h1 = 0.f;
#pragma unroll
        for (int b = 0; b < 64; b += 2) {
            h0 = fmaf(drow[b],     w1r[b],     h0);
            h1 = fmaf(drow[b + 1], w1r[b + 1], h1);
        }
        const float h = b1v + h0 + h1;
        const float s = h / (1.f + __expf(-h));   // silu
        float contrib = s * w2v;
#pragma unroll
        for (int off = 32; off > 0; off >>= 1) contrib += __shfl_down(contrib, off);
        if (lane == 0) partial[a][wave] = contrib;
    }
    __syncthreads();

    if (wave == 0) {
        const int a = lane;
        const float out = partial[a][0] + partial[a][1] + partial[a][2] + partial[a][3] + b2[0];
        const float* tvp = totvec + (size_t)(a0 + a) * 3;
        float px = out * tvp[0], py = out * tvp[1], pz = out * tvp[2];
#pragma unroll
        for (int off = 32; off > 0; off >>= 1) {
            px += __shfl_down(px, off);
            py += __shfl_down(py, off);
            pz += __shfl_down(pz, off);
        }
        if (lane == 0) {
            const int mol = blockIdx.x >> 3;   // 8 blocks per molecule
            unsafeAtomicAdd(&dipole[mol * 3 + 0], px);
            unsafeAtomicAdd(&dipole[mol * 3 + 1], py);
            unsafeAtomicAdd(&dipole[mol * 3 + 2], pz);
        }
    }
}

// ---------------------------------------------------------------------------
extern "C" void kernel_launch(void* const* d_in, const int* in_sizes, int n_in,
                              void* d_out, int out_size, void* d_ws, size_t ws_size,
                              hipStream_t stream)
{
    const float* cart       = (const float*)d_in[0];
    const float* shifts     = (const float*)d_in[1];
    const float* centers    = (const float*)d_in[2];
    const float* widths     = (const float*)d_in[3];
    const float* c_emb      = (const float*)d_in[4];
    const float* W1         = (const float*)d_in[5];
    const float* b1         = (const float*)d_in[6];
    const float* W2         = (const float*)d_in[7];
    const float* b2         = (const float*)d_in[8];
    const int*   species    = (const int*)d_in[10];
    const int*   atom_index = (const int*)d_in[11];

    float* density = (float*)d_ws;                       // [TOTNATOM][64]  4 MB
    float* totvec  = density + (size_t)TOTNATOM * NB;    // [TOTNATOM][3]   192 KB
    float* dipole  = (float*)d_out;                      // [32][3]

    const size_t zero_bytes = ((size_t)TOTNATOM * NB + (size_t)TOTNATOM * 3) * sizeof(float);
    hipMemsetAsync(d_ws, 0, zero_bytes, stream);
    hipMemsetAsync(d_out, 0, (size_t)out_size * sizeof(float), stream);

    hipLaunchKernelGGL(pair_kernel, dim3(NMOL * 8), dim3(1024), 0, stream,
                       cart, shifts, centers, widths, c_emb, species, atom_index,
                       density, totvec);
    hipLaunchKernelGGL(nn_kernel, dim3(TOTNATOM / 64), dim3(256), 0, stream,
                       density, totvec, W1, b1, W2, b2, dipole);
}